// Round 1
// baseline (2087.148 us; speedup 1.0000x reference)
//
#include <hip/hip_runtime.h>

// Linear4bit: out[M,N] = x[M,K] @ ((q[N,K]-8)*scale[N]->fp16)^T + bias[N]
// M=8192 tokens, N=11008 out_features, K=4096 in_features. fp32 in/out.
// Round 1: fused dequant MFMA GEMM (m97-style 128x128x32, 16x16x32 f16 MFMA).

#define M_TOK 8192
#define N_OUT 11008
#define K_IN  4096

constexpr int BM = 128, BN = 128, BK = 32;
constexpr int NBM = M_TOK / BM;   // 64
constexpr int NBN = N_OUT / BN;   // 86
constexpr int LDK = BK + 8;       // 40 halves = 80 B rows: 16B-aligned, bank-spread

using h8 = __attribute__((ext_vector_type(8))) _Float16;
using f4 = __attribute__((ext_vector_type(4))) float;

__global__ __launch_bounds__(256, 2)
void l4b_fused_gemm(const float* __restrict__ x,
                    const int*   __restrict__ qw,
                    const float* __restrict__ scale,
                    const float* __restrict__ bias,
                    float*       __restrict__ out)
{
    __shared__ alignas(16) _Float16 As[BM][LDK];
    __shared__ alignas(16) _Float16 Bs[BN][LDK];

    const int tid = threadIdx.x;
    const int bid = blockIdx.x;
    // mild L2 swizzle: supertiles of 8 bm-rows
    const int chunk = bid / (8 * NBN);
    const int rem   = bid % (8 * NBN);
    const int bm    = chunk * 8 + (rem & 7);
    const int bn    = rem >> 3;

    // staging: 2 threads per row, 16 contiguous K-elements each
    const int row  = tid >> 1;           // 0..127
    const int kseg = (tid & 1) << 4;     // 0 or 16

    const float* xp = x  + (size_t)(bm * BM + row) * K_IN + kseg;
    const int*   qp = qw + (size_t)(bn * BN + row) * K_IN + kseg;
    const float  sc = scale[bn * BN + row];
    const float  sb = -8.0f * sc;        // w = q*sc + sb, then cast to f16 (matches ref)

    // wave tiling: 2x2 waves, each 64x64
    const int wave = tid >> 6;
    const int lane = tid & 63;
    const int wm   = (wave & 1) << 6;
    const int wn   = (wave >> 1) << 6;
    const int m0   = lane & 15;
    const int quad = lane >> 4;
    const int kq   = quad << 3;          // k-offset of this lane's 8 elements

    f4 acc[4][4];
#pragma unroll
    for (int i = 0; i < 4; ++i)
#pragma unroll
        for (int j = 0; j < 4; ++j)
            acc[i][j] = (f4)0.0f;

    for (int k0 = 0; k0 < K_IN; k0 += BK) {
        const float4* xv = (const float4*)(xp + k0);
        const int4*   qv = (const int4*)(qp + k0);
        float4 a0 = xv[0], a1 = xv[1], a2 = xv[2], a3 = xv[3];
        int4   q0 = qv[0], q1 = qv[1], q2 = qv[2], q3 = qv[3];

        float af[16] = {a0.x,a0.y,a0.z,a0.w, a1.x,a1.y,a1.z,a1.w,
                        a2.x,a2.y,a2.z,a2.w, a3.x,a3.y,a3.z,a3.w};
        int   qi[16] = {q0.x,q0.y,q0.z,q0.w, q1.x,q1.y,q1.z,q1.w,
                        q2.x,q2.y,q2.z,q2.w, q3.x,q3.y,q3.z,q3.w};

        h8 alo, ahi, blo, bhi;
#pragma unroll
        for (int i = 0; i < 8; ++i) {
            alo[i] = (_Float16)af[i];
            ahi[i] = (_Float16)af[i + 8];
            blo[i] = (_Float16)fmaf((float)qi[i],     sc, sb);
            bhi[i] = (_Float16)fmaf((float)qi[i + 8], sc, sb);
        }

        __syncthreads();   // previous tile fully consumed
        *(h8*)&As[row][kseg]     = alo;
        *(h8*)&As[row][kseg + 8] = ahi;
        *(h8*)&Bs[row][kseg]     = blo;
        *(h8*)&Bs[row][kseg + 8] = bhi;
        __syncthreads();   // tile ready

        h8 afrag[4], bfrag[4];
#pragma unroll
        for (int i = 0; i < 4; ++i) {
            afrag[i] = *(const h8*)&As[wm + i * 16 + m0][kq];
            bfrag[i] = *(const h8*)&Bs[wn + i * 16 + m0][kq];
        }
#pragma unroll
        for (int i = 0; i < 4; ++i)
#pragma unroll
            for (int j = 0; j < 4; ++j)
                acc[i][j] = __builtin_amdgcn_mfma_f32_16x16x32_f16(
                    afrag[i], bfrag[j], acc[i][j], 0, 0, 0);
    }

    // epilogue: C/D layout col=lane&15, row=quad*4+reg  [m89-verified]
    const int crow = bm * BM + wm + quad * 4;
    const int ccol = bn * BN + wn + m0;
    float bv[4];
#pragma unroll
    for (int j = 0; j < 4; ++j) bv[j] = bias[ccol + j * 16];

#pragma unroll
    for (int i = 0; i < 4; ++i) {
#pragma unroll
        for (int r = 0; r < 4; ++r) {
            float* op = out + (size_t)(crow + i * 16 + r) * N_OUT + ccol;
#pragma unroll
            for (int j = 0; j < 4; ++j)
                op[j * 16] = acc[i][j][r] + bv[j];
        }
    }
}

extern "C" void kernel_launch(void* const* d_in, const int* in_sizes, int n_in,
                              void* d_out, int out_size, void* d_ws, size_t ws_size,
                              hipStream_t stream) {
    const float* x     = (const float*)d_in[0];
    const int*   qw    = (const int*)d_in[1];
    const float* scale = (const float*)d_in[2];
    const float* bias  = (const float*)d_in[3];
    float*       out   = (float*)d_out;

    l4b_fused_gemm<<<dim3(NBM * NBN), dim3(256), 0, stream>>>(x, qw, scale, bias, out);
}

// Round 2
// 1472.796 us; speedup vs baseline: 1.4171x; 1.4171x over previous
//
#include <hip/hip_runtime.h>

// Linear4bit: out[M,N] = x[M,K] @ ((q[N,K]-8)*scale[N]->fp16)^T + bias[N]
// M=8192, N=11008, K=4096. fp32 in/out.
// R2: prologue converts x->f16 and w->f16 (bit-exact vs ref) into d_ws;
//     main GEMM is m97-style 128x128x32 with global_load_lds(16B) staging
//     and XOR-swizzled LDS (conflict-free ds_read_b128).

#define M_TOK 8192
#define N_OUT 11008
#define K_IN  4096

constexpr int BM = 128, BN = 128, BK = 32;
constexpr int NBM = M_TOK / BM;   // 64
constexpr int NBN = N_OUT / BN;   // 86

using h8 = __attribute__((ext_vector_type(8))) _Float16;
using f4 = __attribute__((ext_vector_type(4))) float;

typedef __attribute__((address_space(3))) void       lds_void;
typedef const __attribute__((address_space(1))) void glb_void;

// ---------- prologue 1: x f32 -> f16 (33.5M elems, 8/thread) ----------
__global__ __launch_bounds__(256)
void cvt_x_f16(const float* __restrict__ x, _Float16* __restrict__ x16) {
    size_t idx = ((size_t)blockIdx.x * 256 + threadIdx.x) * 8;
    float4 a = *(const float4*)(x + idx);
    float4 b = *(const float4*)(x + idx + 4);
    h8 o;
    o[0] = (_Float16)a.x; o[1] = (_Float16)a.y; o[2] = (_Float16)a.z; o[3] = (_Float16)a.w;
    o[4] = (_Float16)b.x; o[5] = (_Float16)b.y; o[6] = (_Float16)b.z; o[7] = (_Float16)b.w;
    *(h8*)(x16 + idx) = o;
}

// ---------- prologue 2: w f16 = fp16((q-8)*scale), one block per row ----------
__global__ __launch_bounds__(256)
void cvt_w_f16(const int* __restrict__ qw, const float* __restrict__ scale,
               _Float16* __restrict__ w16) {
    const int row = blockIdx.x;
    const float sc = scale[row];
    const float sb = -8.0f * sc;               // exact (power-of-2 multiple)
    const int*   qp = qw  + (size_t)row * K_IN + threadIdx.x * 16;
    _Float16*    wp = w16 + (size_t)row * K_IN + threadIdx.x * 16;
    int4 q0 = ((const int4*)qp)[0], q1 = ((const int4*)qp)[1];
    int4 q2 = ((const int4*)qp)[2], q3 = ((const int4*)qp)[3];
    int qi[16] = {q0.x,q0.y,q0.z,q0.w, q1.x,q1.y,q1.z,q1.w,
                  q2.x,q2.y,q2.z,q2.w, q3.x,q3.y,q3.z,q3.w};
    h8 lo, hi;
#pragma unroll
    for (int j = 0; j < 8; ++j) {
        lo[j] = (_Float16)fmaf((float)qi[j],     sc, sb);  // == fp16((q-8)*sc)
        hi[j] = (_Float16)fmaf((float)qi[j + 8], sc, sb);
    }
    *(h8*)wp       = lo;
    *(h8*)(wp + 8) = hi;
}

// ---------- main GEMM: f16 x f16 -> f32, global_load_lds staging ----------
__global__ __launch_bounds__(256, 3)
void l4b_gemm16(const _Float16* __restrict__ x16, const _Float16* __restrict__ w16,
                const float* __restrict__ bias, float* __restrict__ out)
{
    __shared__ alignas(16) _Float16 As[BM * BK];   // 8 KB, XOR-swizzled chunks
    __shared__ alignas(16) _Float16 Bs[BN * BK];   // 8 KB

    const int tid = threadIdx.x;
    const int bid = blockIdx.x;
    const int chunk = bid / (8 * NBN);
    const int rem   = bid % (8 * NBN);
    const int bm    = chunk * 8 + (rem & 7);
    const int bn    = rem >> 3;

    const int wave = tid >> 6;
    const int lane = tid & 63;

    // --- staging addressing: lane i -> LDS base+i*16 (HW-fixed); we permute
    // the GLOBAL source so LDS holds chunk c at phys pos c ^ ((row>>1)&3).
    const int r_loc  = lane >> 2;                       // 0..15 within slice
    const int c_log  = (lane & 3) ^ ((lane >> 3) & 3);  // swizzled source chunk
    const _Float16* gA = x16 + (size_t)(bm * BM + wave * 32 + r_loc) * K_IN + (c_log << 3);
    const _Float16* gB = w16 + (size_t)(bn * BN + wave * 32 + r_loc) * K_IN + (c_log << 3);
    _Float16* ldsA = As + wave * 1024;                  // 2 slices of 512 halves
    _Float16* ldsB = Bs + wave * 1024;

    // --- compute addressing: 2x2 waves, 64x64 each, 4x4 16x16x32 MFMAs
    const int m0   = lane & 15;
    const int quad = lane >> 4;
    const int wm   = (wave & 1) << 6;
    const int wn   = (wave >> 1) << 6;
    // phys chunk byte-offset for logical chunk `quad` at rows == m0 (mod 16)
    const int swq  = (quad ^ ((m0 >> 1) & 3)) << 4;

    f4 acc[4][4];
#pragma unroll
    for (int i = 0; i < 4; ++i)
#pragma unroll
        for (int j = 0; j < 4; ++j)
            acc[i][j] = (f4)0.0f;

    for (int k0 = 0; k0 < K_IN; k0 += BK) {
        __syncthreads();   // previous tile fully consumed
        __builtin_amdgcn_global_load_lds((glb_void*)(gA + k0),              (lds_void*)ldsA,         16, 0, 0);
        __builtin_amdgcn_global_load_lds((glb_void*)(gA + k0 + 16 * K_IN), (lds_void*)(ldsA + 512), 16, 0, 0);
        __builtin_amdgcn_global_load_lds((glb_void*)(gB + k0),              (lds_void*)ldsB,         16, 0, 0);
        __builtin_amdgcn_global_load_lds((glb_void*)(gB + k0 + 16 * K_IN), (lds_void*)(ldsB + 512), 16, 0, 0);
        __syncthreads();   // tile ready (compiler drains vmcnt before barrier)

        h8 af[4], bf[4];
#pragma unroll
        for (int i = 0; i < 4; ++i) {
            af[i] = *(const h8*)((const char*)As + ((wm + (i << 4) + m0) << 6) + swq);
            bf[i] = *(const h8*)((const char*)Bs + ((wn + (i << 4) + m0) << 6) + swq);
        }
#pragma unroll
        for (int i = 0; i < 4; ++i)
#pragma unroll
            for (int j = 0; j < 4; ++j)
                acc[i][j] = __builtin_amdgcn_mfma_f32_16x16x32_f16(
                    af[i], bf[j], acc[i][j], 0, 0, 0);
    }

    // epilogue: C/D layout col=lane&15, row=quad*4+reg  [m89-verified]
    const int crow = bm * BM + wm + quad * 4;
    const int ccol = bn * BN + wn + m0;
    float bv[4];
#pragma unroll
    for (int j = 0; j < 4; ++j) bv[j] = bias[ccol + j * 16];

#pragma unroll
    for (int i = 0; i < 4; ++i) {
#pragma unroll
        for (int r = 0; r < 4; ++r) {
            float* op = out + (size_t)(crow + i * 16 + r) * N_OUT + ccol;
#pragma unroll
            for (int j = 0; j < 4; ++j)
                op[j * 16] = acc[i][j][r] + bv[j];
        }
    }
}

// ---------- fallback (R1 fused kernel) if ws is too small ----------
constexpr int LDK = BK + 8;
__global__ __launch_bounds__(256, 2)
void l4b_fused_gemm(const float* __restrict__ x,
                    const int*   __restrict__ qw,
                    const float* __restrict__ scale,
                    const float* __restrict__ bias,
                    float*       __restrict__ out)
{
    __shared__ alignas(16) _Float16 As[BM][LDK];
    __shared__ alignas(16) _Float16 Bs[BN][LDK];

    const int tid = threadIdx.x;
    const int bid = blockIdx.x;
    const int chunk = bid / (8 * NBN);
    const int rem   = bid % (8 * NBN);
    const int bm    = chunk * 8 + (rem & 7);
    const int bn    = rem >> 3;

    const int row  = tid >> 1;
    const int kseg = (tid & 1) << 4;

    const float* xp = x  + (size_t)(bm * BM + row) * K_IN + kseg;
    const int*   qp = qw + (size_t)(bn * BN + row) * K_IN + kseg;
    const float  sc = scale[bn * BN + row];
    const float  sb = -8.0f * sc;

    const int wave = tid >> 6;
    const int lane = tid & 63;
    const int wm   = (wave & 1) << 6;
    const int wn   = (wave >> 1) << 6;
    const int m0   = lane & 15;
    const int quad = lane >> 4;
    const int kq   = quad << 3;

    f4 acc[4][4];
#pragma unroll
    for (int i = 0; i < 4; ++i)
#pragma unroll
        for (int j = 0; j < 4; ++j)
            acc[i][j] = (f4)0.0f;

    for (int k0 = 0; k0 < K_IN; k0 += BK) {
        const float4* xv = (const float4*)(xp + k0);
        const int4*   qv = (const int4*)(qp + k0);
        float4 a0 = xv[0], a1 = xv[1], a2 = xv[2], a3 = xv[3];
        int4   q0 = qv[0], q1 = qv[1], q2 = qv[2], q3 = qv[3];
        float af[16] = {a0.x,a0.y,a0.z,a0.w, a1.x,a1.y,a1.z,a1.w,
                        a2.x,a2.y,a2.z,a2.w, a3.x,a3.y,a3.z,a3.w};
        int   qi[16] = {q0.x,q0.y,q0.z,q0.w, q1.x,q1.y,q1.z,q1.w,
                        q2.x,q2.y,q2.z,q2.w, q3.x,q3.y,q3.z,q3.w};
        h8 alo, ahi, blo, bhi;
#pragma unroll
        for (int i = 0; i < 8; ++i) {
            alo[i] = (_Float16)af[i];
            ahi[i] = (_Float16)af[i + 8];
            blo[i] = (_Float16)fmaf((float)qi[i],     sc, sb);
            bhi[i] = (_Float16)fmaf((float)qi[i + 8], sc, sb);
        }
        __syncthreads();
        *(h8*)&As[row][kseg]     = alo;
        *(h8*)&As[row][kseg + 8] = ahi;
        *(h8*)&Bs[row][kseg]     = blo;
        *(h8*)&Bs[row][kseg + 8] = bhi;
        __syncthreads();
        h8 afr[4], bfr[4];
#pragma unroll
        for (int i = 0; i < 4; ++i) {
            afr[i] = *(const h8*)&As[wm + i * 16 + m0][kq];
            bfr[i] = *(const h8*)&Bs[wn + i * 16 + m0][kq];
        }
#pragma unroll
        for (int i = 0; i < 4; ++i)
#pragma unroll
            for (int j = 0; j < 4; ++j)
                acc[i][j] = __builtin_amdgcn_mfma_f32_16x16x32_f16(
                    afr[i], bfr[j], acc[i][j], 0, 0, 0);
    }

    const int crow = bm * BM + wm + quad * 4;
    const int ccol = bn * BN + wn + m0;
    float bv[4];
#pragma unroll
    for (int j = 0; j < 4; ++j) bv[j] = bias[ccol + j * 16];
#pragma unroll
    for (int i = 0; i < 4; ++i)
#pragma unroll
        for (int r = 0; r < 4; ++r) {
            float* op = out + (size_t)(crow + i * 16 + r) * N_OUT + ccol;
#pragma unroll
            for (int j = 0; j < 4; ++j)
                op[j * 16] = acc[i][j][r] + bv[j];
        }
}

extern "C" void kernel_launch(void* const* d_in, const int* in_sizes, int n_in,
                              void* d_out, int out_size, void* d_ws, size_t ws_size,
                              hipStream_t stream) {
    const float* x     = (const float*)d_in[0];
    const int*   qw    = (const int*)d_in[1];
    const float* scale = (const float*)d_in[2];
    const float* bias  = (const float*)d_in[3];
    float*       out   = (float*)d_out;

    const size_t x16_bytes = (size_t)M_TOK * K_IN * 2;               // 67,108,864
    const size_t w16_bytes = (size_t)N_OUT * K_IN * 2;               // 90,177,536
    if (ws_size >= x16_bytes + w16_bytes) {
        _Float16* x16 = (_Float16*)d_ws;
        _Float16* w16 = (_Float16*)((char*)d_ws + x16_bytes);
        cvt_x_f16<<<dim3((M_TOK * K_IN) / (256 * 8)), dim3(256), 0, stream>>>(x, x16);
        cvt_w_f16<<<dim3(N_OUT), dim3(256), 0, stream>>>(qw, scale, w16);
        l4b_gemm16<<<dim3(NBM * NBN), dim3(256), 0, stream>>>(x16, w16, bias, out);
    } else {
        l4b_fused_gemm<<<dim3(NBM * NBN), dim3(256), 0, stream>>>(x, qw, scale, bias, out);
    }
}